// Round 1
// baseline (520.828 us; speedup 1.0000x reference)
//
#include <hip/hip_runtime.h>

// VQ-VAE vector quantization forward:
//   x: [32,4096,64] fp32, W: [1024,64] fp32
//   out: [quantized_st (8388608 f32), loss, perplexity, usage]
//
// ws layout: [0,4096)  u32 counts[1024]
//            [4096,4104) double sse
//            [8192,12288) float wsq[1024]

constexpr int D = 64;
constexpr int K = 1024;

__global__ __launch_bounds__(256) void vq_init(const float* __restrict__ W,
                                               unsigned int* __restrict__ counts,
                                               float* __restrict__ wsq,
                                               double* __restrict__ sse) {
  int i = blockIdx.x * 256 + threadIdx.x;
  if (i < K) {
    const float4* wv = reinterpret_cast<const float4*>(W + i * D);
    float s = 0.f;
#pragma unroll
    for (int j = 0; j < 16; ++j) {
      float4 v = wv[j];
      s = fmaf(v.x, v.x, s);
      s = fmaf(v.y, v.y, s);
      s = fmaf(v.z, v.z, s);
      s = fmaf(v.w, v.w, s);
    }
    wsq[i] = s;
    counts[i] = 0u;
  }
  if (i == 0) sse[0] = 0.0;
}

__global__ __launch_bounds__(256) void vq_main(const float* __restrict__ x,
                                               const float* __restrict__ W,
                                               const float* __restrict__ wsq,
                                               unsigned int* __restrict__ counts,
                                               double* __restrict__ sse,
                                               float* __restrict__ out) {
  __shared__ unsigned int hist[K];
  __shared__ float red[4];
  for (int i = threadIdx.x; i < K; i += 256) hist[i] = 0u;
  __syncthreads();

  const int t = blockIdx.x * 256 + threadIdx.x;

  // Load this token's 64 features into registers.
  float xr[D];
  const float4* xv = reinterpret_cast<const float4*>(x + (size_t)t * D);
#pragma unroll
  for (int j = 0; j < 16; ++j) reinterpret_cast<float4*>(xr)[j] = xv[j];

  // Argmin over codes of  score = ||w||^2 - 2 x.w   (||x||^2 constant shift
  // dropped -> no large-magnitude cancellation noise; argmin identical).
  float best = 3.0e38f;
  int bidx = 0;
  for (int c = 0; c < K; ++c) {
    const float4* wv = reinterpret_cast<const float4*>(W + c * D);  // wave-uniform -> s_load
    float a0 = 0.f, a1 = 0.f, a2 = 0.f, a3 = 0.f;
#pragma unroll
    for (int j = 0; j < 16; ++j) {
      float4 w4 = wv[j];
      a0 = fmaf(xr[4 * j + 0], w4.x, a0);
      a1 = fmaf(xr[4 * j + 1], w4.y, a1);
      a2 = fmaf(xr[4 * j + 2], w4.z, a2);
      a3 = fmaf(xr[4 * j + 3], w4.w, a3);
    }
    float dot = (a0 + a1) + (a2 + a3);
    float score = fmaf(-2.0f, dot, wsq[c]);
    if (score < best) { best = score; bidx = c; }  // keeps first index on tie
  }

  atomicAdd(&hist[bidx], 1u);

  // Epilogue: out = x + (q - x), sse += (q - x)^2
  const float4* qv = reinterpret_cast<const float4*>(W + (size_t)bidx * D);
  float4* ov = reinterpret_cast<float4*>(out + (size_t)t * D);
  float lsse = 0.f;
#pragma unroll
  for (int j = 0; j < 16; ++j) {
    float4 q4 = qv[j];
    float4 x4 = reinterpret_cast<const float4*>(xr)[j];
    float dx = q4.x - x4.x, dy = q4.y - x4.y, dz = q4.z - x4.z, dw = q4.w - x4.w;
    lsse = fmaf(dx, dx, lsse);
    lsse = fmaf(dy, dy, lsse);
    lsse = fmaf(dz, dz, lsse);
    lsse = fmaf(dw, dw, lsse);
    float4 o4;
    o4.x = x4.x + dx;
    o4.y = x4.y + dy;
    o4.z = x4.z + dz;
    o4.w = x4.w + dw;
    ov[j] = o4;
  }

  // Block-reduce sse (wave shuffle over 64 lanes, then 4 waves via LDS).
  float s = lsse;
#pragma unroll
  for (int off = 32; off > 0; off >>= 1) s += __shfl_down(s, off, 64);
  const int wave = threadIdx.x >> 6, lane = threadIdx.x & 63;
  if (lane == 0) red[wave] = s;
  __syncthreads();  // also orders hist atomics before the flush below
  if (threadIdx.x == 0) {
    float bs = (red[0] + red[1]) + (red[2] + red[3]);
    atomicAdd(sse, (double)bs);
  }
  for (int i = threadIdx.x; i < K; i += 256) {
    unsigned int h = hist[i];
    if (h) atomicAdd(&counts[i], h);
  }
}

__global__ __launch_bounds__(1024) void vq_final(const unsigned int* __restrict__ counts,
                                                 const double* __restrict__ sse,
                                                 float* __restrict__ out_tail,
                                                 int n_tokens) {
  __shared__ double sd[16];
  __shared__ int su[16];
  const int i = threadIdx.x;
  const unsigned int c = counts[i];
  const float p = (float)c * (1.0f / (float)n_tokens);
  const float term = p * logf(p + 1e-10f);  // fp32 elementwise, like the reference
  double s = (double)term;
  int u = (c >= 1u) ? 1 : 0;
#pragma unroll
  for (int off = 32; off > 0; off >>= 1) {
    s += __shfl_down(s, off, 64);
    u += __shfl_down(u, off, 64);
  }
  const int wave = i >> 6, lane = i & 63;
  if (lane == 0) { sd[wave] = s; su[wave] = u; }
  __syncthreads();
  if (wave == 0) {
    double s2 = (lane < 16) ? sd[lane] : 0.0;
    int u2 = (lane < 16) ? su[lane] : 0;
#pragma unroll
    for (int off = 8; off > 0; off >>= 1) {
      s2 += __shfl_down(s2, off, 64);
      u2 += __shfl_down(u2, off, 64);
    }
    if (lane == 0) {
      double mean = sse[0] / ((double)n_tokens * (double)D);
      out_tail[0] = 3.0f * (float)mean;        // q_latent + 2*e_latent
      out_tail[1] = expf(-(float)s2);          // perplexity
      out_tail[2] = (float)u2;                 // usage
    }
  }
}

extern "C" void kernel_launch(void* const* d_in, const int* in_sizes, int n_in,
                              void* d_out, int out_size, void* d_ws, size_t ws_size,
                              hipStream_t stream) {
  const float* x = (const float*)d_in[0];
  const float* W = (const float*)d_in[1];
  float* out = (float*)d_out;

  unsigned int* counts = (unsigned int*)d_ws;
  double* sse = (double*)((char*)d_ws + 4096);
  float* wsq = (float*)((char*)d_ws + 8192);

  const int n_tokens = in_sizes[0] / D;  // 131072
  const int blocks = (n_tokens + 255) / 256;

  vq_init<<<(K + 255) / 256, 256, 0, stream>>>(W, counts, wsq, sse);
  vq_main<<<blocks, 256, 0, stream>>>(x, W, wsq, counts, sse, out);
  vq_final<<<1, 1024, 0, stream>>>(counts, sse, out + (size_t)n_tokens * D, n_tokens);
}

// Round 2
// 150.796 us; speedup vs baseline: 3.4539x; 3.4539x over previous
//
#include <hip/hip_runtime.h>

// VQ-VAE forward via bf16 MFMA distance scan.
//   score(token,code) = dot(x,w) - ||w||^2/2   (maximize == argmin distance)
//   dist_best = -2*score_best;  SSE = sum(xsq) + sum(dist_best)
//
// ws layout: [0,4096) u32 counts[1024] | [4096,4104) double sse
//            [8192,12288) float wnh[1024] (= -0.5||w||^2)
//            [16384,16384+131072) bf16 W_bf[1024][64]

typedef __bf16          bf16x8  __attribute__((ext_vector_type(8)));
typedef float           f32x4   __attribute__((ext_vector_type(4)));
typedef unsigned short  ushortx8 __attribute__((ext_vector_type(8)));

constexpr int D = 64;
constexpr int K = 1024;
constexpr int CHUNK = 256;        // codes staged in LDS per pass
constexpr int SLOTS = CHUNK * 9;  // 16B slots: 8 data + 1 pad per code row (144B stride)

__device__ __forceinline__ unsigned short f2bf(float f) {
  unsigned u = __builtin_bit_cast(unsigned, f);
  u = (u + 0x7fffu + ((u >> 16) & 1u)) >> 16;  // RNE
  return (unsigned short)u;
}

__global__ __launch_bounds__(256) void vq_init(const float* __restrict__ W,
                                               unsigned* __restrict__ counts,
                                               float* __restrict__ wnh,
                                               double* __restrict__ sse,
                                               ushortx8* __restrict__ wbf) {
  const int c = blockIdx.x * 256 + threadIdx.x;  // 0..1023
  const float4* row = reinterpret_cast<const float4*>(W + c * D);
  float s = 0.f;
#pragma unroll
  for (int j = 0; j < 8; ++j) {
    float4 v0 = row[2 * j], v1 = row[2 * j + 1];
    s = fmaf(v0.x, v0.x, s); s = fmaf(v0.y, v0.y, s);
    s = fmaf(v0.z, v0.z, s); s = fmaf(v0.w, v0.w, s);
    s = fmaf(v1.x, v1.x, s); s = fmaf(v1.y, v1.y, s);
    s = fmaf(v1.z, v1.z, s); s = fmaf(v1.w, v1.w, s);
    ushortx8 p;
    p[0] = f2bf(v0.x); p[1] = f2bf(v0.y); p[2] = f2bf(v0.z); p[3] = f2bf(v0.w);
    p[4] = f2bf(v1.x); p[5] = f2bf(v1.y); p[6] = f2bf(v1.z); p[7] = f2bf(v1.w);
    wbf[c * 8 + j] = p;
  }
  wnh[c] = -0.5f * s;
  counts[c] = 0u;
  if (c == 0) *sse = 0.0;
}

// 256 threads = 4 waves; 32 tokens/wave (2 A-tiles of 16) -> 128 tokens/block.
__global__ __launch_bounds__(256, 3) void vq_main(const float* __restrict__ x,
                                                  const float* __restrict__ Wf,
                                                  const ushortx8* __restrict__ wbf,
                                                  const float* __restrict__ wnh,
                                                  unsigned* __restrict__ counts,
                                                  double* __restrict__ sse,
                                                  float* __restrict__ out) {
  __shared__ uint4 s_w[SLOTS];        // 36864 B, 144B/code row (bank-balanced)
  __shared__ float s_wnh[CHUNK];      // 1 KB
  __shared__ unsigned s_hist[K];      // 4 KB
  __shared__ unsigned s_idx[128];     // 512 B
  __shared__ float s_red[4];

  const int tid = threadIdx.x;
  const int wv = tid >> 6, lane = tid & 63;
  const int g = lane >> 4, nl = lane & 15;
  const int tokwg = blockIdx.x * 128;

  for (int i = tid; i < K; i += 256) s_hist[i] = 0u;

  // A fragments: x[tile 16 tokens x 32 k] per (tt,s); lane holds
  // A[m=lane&15][k=(lane>>4)*8 + j].  Also accumulate sum(x^2).
  bf16x8 afrag[2][2];
  float xsq = 0.f;
#pragma unroll
  for (int tt = 0; tt < 2; ++tt) {
#pragma unroll
    for (int s = 0; s < 2; ++s) {
      const float* px = x + (size_t)(tokwg + wv * 32 + tt * 16 + nl) * D + s * 32 + g * 8;
      float4 v0 = *reinterpret_cast<const float4*>(px);
      float4 v1 = *reinterpret_cast<const float4*>(px + 4);
      xsq = fmaf(v0.x, v0.x, xsq); xsq = fmaf(v0.y, v0.y, xsq);
      xsq = fmaf(v0.z, v0.z, xsq); xsq = fmaf(v0.w, v0.w, xsq);
      xsq = fmaf(v1.x, v1.x, xsq); xsq = fmaf(v1.y, v1.y, xsq);
      xsq = fmaf(v1.z, v1.z, xsq); xsq = fmaf(v1.w, v1.w, xsq);
      ushortx8 p;
      p[0] = f2bf(v0.x); p[1] = f2bf(v0.y); p[2] = f2bf(v0.z); p[3] = f2bf(v0.w);
      p[4] = f2bf(v1.x); p[5] = f2bf(v1.y); p[6] = f2bf(v1.z); p[7] = f2bf(v1.w);
      afrag[tt][s] = __builtin_bit_cast(bf16x8, p);
    }
  }

  float best[2][4];
  unsigned bidx[2][4];
#pragma unroll
  for (int tt = 0; tt < 2; ++tt)
#pragma unroll
    for (int j = 0; j < 4; ++j) { best[tt][j] = -3.0e38f; bidx[tt][j] = 0u; }

  for (int cb = 0; cb < K; cb += CHUNK) {
    __syncthreads();
    // Stage 256 codes of W_bf into LDS with 144B row stride (pad slot unused).
    for (int i = tid; i < SLOTS; i += 256) {
      int code = i / 9, part = i - code * 9;
      uint4 v = make_uint4(0u, 0u, 0u, 0u);
      if (part < 8) v = *reinterpret_cast<const uint4*>(wbf + (size_t)(cb + code) * 8 + part);
      s_w[i] = v;
    }
    s_wnh[tid] = wnh[cb + tid];
    __syncthreads();

#pragma unroll
    for (int ct = 0; ct < CHUNK / 16; ++ct) {
      const float w0 = s_wnh[ct * 16 + nl];
      const int srow = (ct * 16 + nl) * 9;  // B[k][n]: n=lane&15, k=(lane>>4)*8+j
      bf16x8 b0 = __builtin_bit_cast(bf16x8, s_w[srow + g]);
      bf16x8 b1 = __builtin_bit_cast(bf16x8, s_w[srow + 4 + g]);
      const unsigned code0 = (unsigned)(cb + ct * 16 + nl);
#pragma unroll
      for (int tt = 0; tt < 2; ++tt) {
        f32x4 acc = {w0, w0, w0, w0};  // C init = -||w||^2/2 (per col)
        acc = __builtin_amdgcn_mfma_f32_16x16x32_bf16(afrag[tt][0], b0, acc, 0, 0, 0);
        acc = __builtin_amdgcn_mfma_f32_16x16x32_bf16(afrag[tt][1], b1, acc, 0, 0, 0);
#pragma unroll
        for (int j = 0; j < 4; ++j) {
          if (acc[j] > best[tt][j]) { best[tt][j] = acc[j]; bidx[tt][j] = code0; }
        }
      }
    }
  }

  // Cross-lane argmax over the 16 cols (lanes with same quad); C/D row = 4*g+j.
  float ddist = 0.f;
#pragma unroll
  for (int tt = 0; tt < 2; ++tt) {
#pragma unroll
    for (int j = 0; j < 4; ++j) {
      float b = best[tt][j];
      unsigned bi = bidx[tt][j];
#pragma unroll
      for (int off = 1; off < 16; off <<= 1) {
        float ob = __shfl_xor(b, off, 64);
        unsigned oi = __shfl_xor(bi, off, 64);
        if (ob > b || (ob == b && oi < bi)) { b = ob; bi = oi; }
      }
      if (nl == 0) {
        int tl = wv * 32 + tt * 16 + 4 * g + j;
        s_idx[tl] = bi;
        atomicAdd(&s_hist[bi], 1u);
        ddist = fmaf(-2.0f, b, ddist);  // dist = wsq - 2*dot >= 0
      }
    }
  }

  // Block-reduce SSE contribution: sum(x^2) + sum(dist_best).
  float sv = xsq + ddist;
#pragma unroll
  for (int off = 32; off > 0; off >>= 1) sv += __shfl_down(sv, off, 64);
  if (lane == 0) s_red[wv] = sv;
  __syncthreads();
  if (tid == 0) atomicAdd(sse, (double)((s_red[0] + s_red[1]) + (s_red[2] + s_red[3])));

  for (int i = tid; i < K; i += 256) {
    unsigned h = s_hist[i];
    if (h) atomicAdd(&counts[i], h);
  }

  // out = W[idx] (fp32 gather; == x + (q - x) to <=1 ulp).
  const int d4 = tid & 15;
#pragma unroll
  for (int tk = 0; tk < 8; ++tk) {
    int tl = tk * 16 + (tid >> 4);
    unsigned ci = s_idx[tl];
    float4 q = *reinterpret_cast<const float4*>(Wf + ci * D + d4 * 4);
    *reinterpret_cast<float4*>(out + (size_t)(tokwg + tl) * D + d4 * 4) = q;
  }
}

__global__ __launch_bounds__(1024) void vq_final(const unsigned* __restrict__ counts,
                                                 const double* __restrict__ sse,
                                                 float* __restrict__ out_tail,
                                                 int n_tokens) {
  __shared__ double sd[16];
  __shared__ int su[16];
  const int i = threadIdx.x;
  const unsigned c = counts[i];
  const float p = (float)c * (1.0f / (float)n_tokens);
  const float term = p * logf(p + 1e-10f);
  double s = (double)term;
  int u = (c >= 1u) ? 1 : 0;
#pragma unroll
  for (int off = 32; off > 0; off >>= 1) {
    s += __shfl_down(s, off, 64);
    u += __shfl_down(u, off, 64);
  }
  const int wave = i >> 6, lane = i & 63;
  if (lane == 0) { sd[wave] = s; su[wave] = u; }
  __syncthreads();
  if (wave == 0) {
    double s2 = (lane < 16) ? sd[lane] : 0.0;
    int u2 = (lane < 16) ? su[lane] : 0;
#pragma unroll
    for (int off = 8; off > 0; off >>= 1) {
      s2 += __shfl_down(s2, off, 64);
      u2 += __shfl_down(u2, off, 64);
    }
    if (lane == 0) {
      double mean = sse[0] / ((double)n_tokens * (double)D);
      out_tail[0] = 3.0f * (float)mean;  // q_latent + 2*e_latent
      out_tail[1] = expf(-(float)s2);    // perplexity
      out_tail[2] = (float)u2;           // usage
    }
  }
}

extern "C" void kernel_launch(void* const* d_in, const int* in_sizes, int n_in,
                              void* d_out, int out_size, void* d_ws, size_t ws_size,
                              hipStream_t stream) {
  const float* x = (const float*)d_in[0];
  const float* W = (const float*)d_in[1];
  float* out = (float*)d_out;

  unsigned* counts = (unsigned*)d_ws;
  double* sse = (double*)((char*)d_ws + 4096);
  float* wnh = (float*)((char*)d_ws + 8192);
  ushortx8* wbf = (ushortx8*)((char*)d_ws + 16384);

  const int n_tokens = in_sizes[0] / D;  // 131072
  const int blocks = n_tokens / 128;     // 1024

  vq_init<<<K / 256, 256, 0, stream>>>(W, counts, wnh, sse, wbf);
  vq_main<<<blocks, 256, 0, stream>>>(x, W, wbf, wnh, counts, sse, out);
  vq_final<<<1, 1024, 0, stream>>>(counts, sse, out + (size_t)n_tokens * D, n_tokens);
}

// Round 3
// 139.948 us; speedup vs baseline: 3.7216x; 1.0775x over previous
//
#include <hip/hip_runtime.h>

// VQ-VAE forward via bf16 MFMA distance scan.
//   score(token,code) = dot(x,w) - ||w||^2/2   (maximize == argmin distance)
//   dist_best = -2*score_best;  SSE = sum(xsq) + sum(dist_best)
//
// R3: conflict-free swizzled B staging (lane-contiguous ds_read_b128),
//     64 tokens/wave (4 MFMA tile-chains), 4 blocks/CU occupancy.
//
// ws layout: [0,4096) u32 counts[1024] | [4096,4104) double sse
//            [8192,12288) float wnh[1024] (= -0.5||w||^2)
//            [16384,16384+131072) bf16 W_bf[1024][64]

typedef __bf16          bf16x8  __attribute__((ext_vector_type(8)));
typedef float           f32x4   __attribute__((ext_vector_type(4)));
typedef unsigned short  ushortx8 __attribute__((ext_vector_type(8)));

constexpr int D = 64;
constexpr int K = 1024;
constexpr int CHUNK = 256;            // codes staged in LDS per pass
constexpr int TOKB = 256;             // tokens per block (64/wave x 4 waves)

__device__ __forceinline__ unsigned short f2bf(float f) {
  unsigned u = __builtin_bit_cast(unsigned, f);
  u = (u + 0x7fffu + ((u >> 16) & 1u)) >> 16;  // RNE
  return (unsigned short)u;
}

__global__ __launch_bounds__(256) void vq_init(const float* __restrict__ W,
                                               unsigned* __restrict__ counts,
                                               float* __restrict__ wnh,
                                               double* __restrict__ sse,
                                               ushortx8* __restrict__ wbf) {
  const int c = blockIdx.x * 256 + threadIdx.x;  // 0..1023
  const float4* row = reinterpret_cast<const float4*>(W + c * D);
  float s = 0.f;
#pragma unroll
  for (int j = 0; j < 8; ++j) {
    float4 v0 = row[2 * j], v1 = row[2 * j + 1];
    s = fmaf(v0.x, v0.x, s); s = fmaf(v0.y, v0.y, s);
    s = fmaf(v0.z, v0.z, s); s = fmaf(v0.w, v0.w, s);
    s = fmaf(v1.x, v1.x, s); s = fmaf(v1.y, v1.y, s);
    s = fmaf(v1.z, v1.z, s); s = fmaf(v1.w, v1.w, s);
    ushortx8 p;
    p[0] = f2bf(v0.x); p[1] = f2bf(v0.y); p[2] = f2bf(v0.z); p[3] = f2bf(v0.w);
    p[4] = f2bf(v1.x); p[5] = f2bf(v1.y); p[6] = f2bf(v1.z); p[7] = f2bf(v1.w);
    wbf[c * 8 + j] = p;
  }
  wnh[c] = -0.5f * s;
  counts[c] = 0u;
  if (c == 0) *sse = 0.0;
}

// 256 threads = 4 waves; 64 tokens/wave (4 A-tiles of 16) -> 256 tokens/block.
__global__ __launch_bounds__(256, 4) void vq_main(const float* __restrict__ x,
                                                  const float* __restrict__ Wf,
                                                  const uint4* __restrict__ wbf,
                                                  const float* __restrict__ wnh,
                                                  unsigned* __restrict__ counts,
                                                  double* __restrict__ sse,
                                                  float* __restrict__ out) {
  // Swizzled B: for each 16-code tile ct, slot layout is exactly the lane
  // order of the two wave reads: b0 at [ct*128 + lane], b1 at [ct*128+64+lane].
  __shared__ uint4 s_w[CHUNK * 8];     // 32 KB
  __shared__ float s_wnh[CHUNK];       // 1 KB
  __shared__ unsigned s_hist[K];       // 4 KB
  __shared__ unsigned s_idx[TOKB];     // 1 KB
  __shared__ float s_red[4];

  const int tid = threadIdx.x;
  const int wv = tid >> 6, lane = tid & 63;
  const int g = lane >> 4, nl = lane & 15;
  const int tokwg = blockIdx.x * TOKB;

  for (int i = tid; i < K; i += 256) s_hist[i] = 0u;

  // A fragments: lane holds A[m=lane&15][k=(lane>>4)*8+j]; 4 token tiles.
  bf16x8 afrag[4][2];
  float xsq = 0.f;
#pragma unroll
  for (int tt = 0; tt < 4; ++tt) {
#pragma unroll
    for (int s = 0; s < 2; ++s) {
      const float* px = x + (size_t)(tokwg + wv * 64 + tt * 16 + nl) * D + s * 32 + g * 8;
      float4 v0 = *reinterpret_cast<const float4*>(px);
      float4 v1 = *reinterpret_cast<const float4*>(px + 4);
      xsq = fmaf(v0.x, v0.x, xsq); xsq = fmaf(v0.y, v0.y, xsq);
      xsq = fmaf(v0.z, v0.z, xsq); xsq = fmaf(v0.w, v0.w, xsq);
      xsq = fmaf(v1.x, v1.x, xsq); xsq = fmaf(v1.y, v1.y, xsq);
      xsq = fmaf(v1.z, v1.z, xsq); xsq = fmaf(v1.w, v1.w, xsq);
      ushortx8 p;
      p[0] = f2bf(v0.x); p[1] = f2bf(v0.y); p[2] = f2bf(v0.z); p[3] = f2bf(v0.w);
      p[4] = f2bf(v1.x); p[5] = f2bf(v1.y); p[6] = f2bf(v1.z); p[7] = f2bf(v1.w);
      afrag[tt][s] = __builtin_bit_cast(bf16x8, p);
    }
  }

  float best[4][4];
  unsigned bidx[4][4];
#pragma unroll
  for (int tt = 0; tt < 4; ++tt)
#pragma unroll
    for (int j = 0; j < 4; ++j) { best[tt][j] = -3.0e38f; bidx[tt][j] = 0u; }

  for (int cb = 0; cb < K; cb += CHUNK) {
    __syncthreads();
    // Stage 256 codes, swizzled into wave-read order. Global reads are
    // perfectly coalesced (slot index == linear); LDS writes balanced
    // (one lane per bank-quad per phase).
    for (int i = tid; i < CHUNK * 8; i += 256) {
      const int code = i >> 3, part = i & 7;
      const int ct = code >> 4, cnl = code & 15;
      const int half = part >> 2, q = part & 3;
      s_w[ct * 128 + half * 64 + q * 16 + cnl] = wbf[(size_t)(cb + code) * 8 + part];
    }
    s_wnh[tid] = wnh[cb + tid];
    __syncthreads();

#pragma unroll
    for (int ct = 0; ct < CHUNK / 16; ++ct) {
      const float w0 = s_wnh[ct * 16 + nl];
      bf16x8 b0 = __builtin_bit_cast(bf16x8, s_w[ct * 128 + lane]);        // conflict-free
      bf16x8 b1 = __builtin_bit_cast(bf16x8, s_w[ct * 128 + 64 + lane]);   // conflict-free
      const unsigned code0 = (unsigned)(cb + ct * 16 + nl);
      f32x4 acc[4];
#pragma unroll
      for (int tt = 0; tt < 4; ++tt) {
        acc[tt] = (f32x4){w0, w0, w0, w0};  // C init = -||w||^2/2 (per col)
        acc[tt] = __builtin_amdgcn_mfma_f32_16x16x32_bf16(afrag[tt][0], b0, acc[tt], 0, 0, 0);
        acc[tt] = __builtin_amdgcn_mfma_f32_16x16x32_bf16(afrag[tt][1], b1, acc[tt], 0, 0, 0);
      }
#pragma unroll
      for (int tt = 0; tt < 4; ++tt)
#pragma unroll
        for (int j = 0; j < 4; ++j) {
          if (acc[tt][j] > best[tt][j]) { best[tt][j] = acc[tt][j]; bidx[tt][j] = code0; }
        }
    }
  }

  // Cross-lane argmax over the 16 cols; C/D row = 4*g+j, col = nl.
  float ddist = 0.f;
#pragma unroll
  for (int tt = 0; tt < 4; ++tt) {
#pragma unroll
    for (int j = 0; j < 4; ++j) {
      float b = best[tt][j];
      unsigned bi = bidx[tt][j];
#pragma unroll
      for (int off = 1; off < 16; off <<= 1) {
        float ob = __shfl_xor(b, off, 64);
        unsigned oi = __shfl_xor(bi, off, 64);
        if (ob > b || (ob == b && oi < bi)) { b = ob; bi = oi; }
      }
      if (nl == 0) {
        int tl = wv * 64 + tt * 16 + 4 * g + j;
        s_idx[tl] = bi;
        atomicAdd(&s_hist[bi], 1u);
        ddist = fmaf(-2.0f, b, ddist);  // dist = wsq - 2*dot >= 0
      }
    }
  }

  // Block-reduce SSE contribution: sum(x^2) + sum(dist_best).
  float sv = xsq + ddist;
#pragma unroll
  for (int off = 32; off > 0; off >>= 1) sv += __shfl_down(sv, off, 64);
  if (lane == 0) s_red[wv] = sv;
  __syncthreads();  // also publishes s_idx / orders s_hist atomics
  if (tid == 0) atomicAdd(sse, (double)((s_red[0] + s_red[1]) + (s_red[2] + s_red[3])));

  for (int i = tid; i < K; i += 256) {
    unsigned h = s_hist[i];
    if (h) atomicAdd(&counts[i], h);
  }

  // out = W[idx] (fp32 gather; == x + (q - x) to <=1 ulp).
  const int d4 = tid & 15;
#pragma unroll
  for (int tk = 0; tk < 16; ++tk) {
    int tl = tk * 16 + (tid >> 4);
    unsigned ci = s_idx[tl];
    float4 q = *reinterpret_cast<const float4*>(Wf + ci * D + d4 * 4);
    *reinterpret_cast<float4*>(out + (size_t)(tokwg + tl) * D + d4 * 4) = q;
  }
}

__global__ __launch_bounds__(1024) void vq_final(const unsigned* __restrict__ counts,
                                                 const double* __restrict__ sse,
                                                 float* __restrict__ out_tail,
                                                 int n_tokens) {
  __shared__ double sd[16];
  __shared__ int su[16];
  const int i = threadIdx.x;
  const unsigned c = counts[i];
  const float p = (float)c * (1.0f / (float)n_tokens);
  const float term = p * logf(p + 1e-10f);
  double s = (double)term;
  int u = (c >= 1u) ? 1 : 0;
#pragma unroll
  for (int off = 32; off > 0; off >>= 1) {
    s += __shfl_down(s, off, 64);
    u += __shfl_down(u, off, 64);
  }
  const int wave = i >> 6, lane = i & 63;
  if (lane == 0) { sd[wave] = s; su[wave] = u; }
  __syncthreads();
  if (wave == 0) {
    double s2 = (lane < 16) ? sd[lane] : 0.0;
    int u2 = (lane < 16) ? su[lane] : 0;
#pragma unroll
    for (int off = 8; off > 0; off >>= 1) {
      s2 += __shfl_down(s2, off, 64);
      u2 += __shfl_down(u2, off, 64);
    }
    if (lane == 0) {
      double mean = sse[0] / ((double)n_tokens * (double)D);
      out_tail[0] = 3.0f * (float)mean;  // q_latent + 2*e_latent
      out_tail[1] = expf(-(float)s2);    // perplexity
      out_tail[2] = (float)u2;           // usage
    }
  }
}

extern "C" void kernel_launch(void* const* d_in, const int* in_sizes, int n_in,
                              void* d_out, int out_size, void* d_ws, size_t ws_size,
                              hipStream_t stream) {
  const float* x = (const float*)d_in[0];
  const float* W = (const float*)d_in[1];
  float* out = (float*)d_out;

  unsigned* counts = (unsigned*)d_ws;
  double* sse = (double*)((char*)d_ws + 4096);
  float* wnh = (float*)((char*)d_ws + 8192);
  void* wbf = (void*)((char*)d_ws + 16384);

  const int n_tokens = in_sizes[0] / D;  // 131072
  const int blocks = n_tokens / TOKB;    // 512

  vq_init<<<K / 256, 256, 0, stream>>>(W, counts, wnh, sse, (ushortx8*)wbf);
  vq_main<<<blocks, 256, 0, stream>>>(x, W, (const uint4*)wbf, wnh, counts, sse, out);
  vq_final<<<1, 1024, 0, stream>>>(counts, sse, out + (size_t)n_tokens * D, n_tokens);
}